// Round 5
// baseline (149.518 us; speedup 1.0000x reference)
//
#include <hip/hip_runtime.h>
#include <hip/hip_bf16.h>

#define WW 20
#define NW 8192         // 64*128 words
#define VOCAB 256
#define EE 64
#define HH 256
#define K3 768          // 3*HH
#define UNIT 2304       // ushorts per vocab unit (P5) = 4608 B

typedef short bf16x8 __attribute__((ext_vector_type(8)));
typedef float f32x4  __attribute__((ext_vector_type(4)));

__device__ __forceinline__ ushort f2bs(float x) {
    __hip_bfloat16 h = __float2bfloat16(x);
    union { __hip_bfloat16 h; ushort u; } c; c.h = h; return c.u;
}
__device__ __forceinline__ float blo(unsigned u) {
    union { unsigned i; float f; } c; c.i = u << 16; return c.f;
}
__device__ __forceinline__ float bhi(unsigned u) {
    union { unsigned i; float f; } c; c.i = u & 0xffff0000u; return c.f;
}
__device__ __forceinline__ unsigned pack2(float lo, float hi) {
    return (unsigned)f2bs(lo) | ((unsigned)f2bs(hi) << 16);
}

// sliding-window update for one h given this char's 9 bf16 taps.
// j compile-time (fully unrolled caller) so %3/%5 indices and guards fold.
// R17 lesson: do NOT pack the two h lanes into f32x2 -- register-pair
// alignment bloated VGPR to 220 (> the 128 occupancy cliff) and halved
// blocks/CU: conv_pool 29 -> 43.8 us. Scalar STEP stays.
#define STEP(j, qq, t8v, a3, a5, mm1, mm3, mm5) {                        \
    float t0 = blo((qq).x), t1 = bhi((qq).x);                            \
    float t2 = blo((qq).y), t3 = bhi((qq).y);                            \
    float t4 = blo((qq).z), t5 = bhi((qq).z);                            \
    float t6 = blo((qq).w), t7 = bhi((qq).w);                            \
    mm1 = fmaxf(mm1, t0);                                                \
    if ((j) + 1 < WW) a3[((j)+1)%3] = t1;                                \
    a3[(j)%3] += t2;                                                     \
    if ((j) >= 1) { a3[((j)-1)%3] += t3;                                 \
                    mm3 = fmaxf(mm3, a3[((j)-1)%3]); }                   \
    if ((j) + 2 < WW) a5[((j)+2)%5] = t4;                                \
    if ((j) + 1 < WW) a5[((j)+1)%5] += t5;                               \
    a5[(j)%5] += t6;                                                     \
    if ((j) >= 1) a5[((j)-1)%5] += t7;                                   \
    if ((j) >= 2) { a5[((j)-2)%5] += (t8v);                              \
                    mm5 = fmaxf(mm5, a5[((j)-2)%5]); }                   \
}

// ---------------------------------------------------------------------------
// P5 layout (per vocab v, 2304 ushorts = 4608 B): 32 slices s of 144 B:
//   [hl 0..7][taps 0..7] (8 x 16 B rows), then [tap8 for hl 0..7] (16 B).
//   j = s*72 + r;  r<64: tap=r&7, h=s*8+(r>>3);  r>=64: tap=8, h=s*8+(r-64).
// bf16 kept deliberately: R12's f32 table doubled staging+LDS traffic and
// produced 1.24e7 bank-conflict cycles (144-B f32 stride -> 8 bank classes).
//
// R14 lesson: do NOT fuse prep into build_tables. The direct w-gather makes
// consecutive lanes take different tap branches (divergent, scattered
// addresses, repeated 64x) and cost +6.6 us. The wTp round-trip is the
// right design: scatter once at 0.6 MB, re-read coalesced.
// ---------------------------------------------------------------------------

// K0: prep. blocks 0..575: wTp[e][j] f32 (P5 column order);
//          blocks 576..767: lw f32 -> bf16.
__global__ __launch_bounds__(256) void prep(
        const float* __restrict__ w1,
        const float* __restrict__ w3,
        const float* __restrict__ w5,
        const float* __restrict__ lw,
        float* __restrict__ wTp,
        ushort* __restrict__ lwb) {
    const int bid = blockIdx.x;
    if (bid < 576) {
        int idx = bid * 256 + threadIdx.x;      // = e*2304 + j, 147456 total
        int e = idx / UNIT;
        int j = idx - e * UNIT;
        int s = j / 72, r = j - s * 72;
        int tap, h;
        if (r < 64) { tap = r & 7; h = s*8 + (r >> 3); }
        else        { tap = 8;     h = s*8 + (r - 64); }
        float v;
        if (tap == 0)      v = w1[h*EE + e];
        else if (tap <= 3) v = w3[(h*EE + e)*3 + (tap-1)];
        else               v = w5[(h*EE + e)*5 + (tap-4)];
        wTp[idx] = v;
    } else {
        int i = ((bid - 576) * 256 + threadIdx.x) * 4;
        float4 v = *(const float4*)(lw + i);
        ushort4 o4;
        o4.x = f2bs(v.x); o4.y = f2bs(v.y); o4.z = f2bs(v.z); o4.w = f2bs(v.w);
        *(ushort4*)(lwb + i) = o4;
    }
}

// K1: P5[v][j] = sum_e emb[v][e] * wTp[e][j]. 4 vocab rows per block,
// grid (64, 9) x 256 thr. Coalesced streaming reads/writes.
__global__ __launch_bounds__(256) void build_tables(
        const float* __restrict__ emb,
        const float* __restrict__ wTp,
        ushort* __restrict__ P5) {
    __shared__ float emb_s[4][EE];
    const int v0 = blockIdx.x * 4;
    const int j  = blockIdx.y * 256 + threadIdx.x;
    const int t  = threadIdx.x;
    emb_s[t >> 6][t & 63] = emb[v0*EE + t];
    __syncthreads();

    float a0 = 0.f, a1 = 0.f, a2 = 0.f, a3 = 0.f;
    const float* wp = wTp + j;
    #pragma unroll 8
    for (int e = 0; e < EE; ++e) {
        float w = wp[e * UNIT];
        a0 += emb_s[0][e] * w; a1 += emb_s[1][e] * w;
        a2 += emb_s[2][e] * w; a3 += emb_s[3][e] * w;
    }
    P5[(size_t)(v0+0)*UNIT + j] = f2bs(a0);
    P5[(size_t)(v0+1)*UNIT + j] = f2bs(a1);
    P5[(size_t)(v0+2)*UNIT + j] = f2bs(a2);
    P5[(size_t)(v0+3)*UNIT + j] = f2bs(a3);
}

// ---------------------------------------------------------------------------
// K2: conv+relu+maxpool. R18: conv is LDS-PIPE-bound (R17 counters: VALUBusy
// 37%, HBM 5%, bank-conflict ~19% of cycles), so the tap8 ds_read_b32 moved
// to GLOBAL (P5 = 1.18 MB, L2-resident per XCD; lesson: don't LDS-stage
// what L2-fits). LDS per char: 3 ops/36 B -> 2 ops/32 B (~-20% pipe cycles),
// tap8 bank conflicts gone, staging 9 -> 8 chunks/thread. The 144-B LDS
// stride is KEPT (tap8 row now dead pad): at stride 128 B all rows would
// alias to one bank-chunk class (16-way conflict); 144 B spreads chars over
// all 8 classes. t8 ring-prefetched distance-3 from global (~270 cy cover
// vs ~200 cy L2 latency), compile-time ring indices (rule #20).
// __launch_bounds__(256,4) pins VGPR <= 128: 4 blocks/CU is mandatory
// (R17: 220 VGPR -> 2 blocks/CU -> +15 us).
// ---------------------------------------------------------------------------
__global__ __launch_bounds__(256, 4) void conv_pool(
        const int* __restrict__ chars,
        const ushort* __restrict__ P5,
        const float* __restrict__ b1,
        const float* __restrict__ b3,
        const float* __restrict__ b5,
        ushort* __restrict__ outs) {
    __shared__ uint4 tileq[2304];          // 36864 B; per v: 128 B used + 16 pad
    const int t = threadIdx.x;
    const int g = blockIdx.x;              // word group 0..31 (256 words)
    const int s = blockIdx.y;              // h slice   0..31

    {   // stage taps 0..7 only: 2048 16-B chunks, 8 per thread (v=c>>3, k=c&7)
        const char* src = (const char*)P5 + (size_t)s * 144;
        char* dst = (char*)tileq;
        #pragma unroll
        for (int i = 0; i < 8; ++i) {
            int c = i*256 + t;
            int v = c >> 3, k = c & 7;
            *(uint4*)(dst + v*144 + k*16) =
                *(const uint4*)(src + (size_t)v*4608 + k*16);
        }
    }
    __syncthreads();

    const int p   = t & 3;                 // hl pair 0..3
    const int wl0 = t >> 2;                // word lane 0..63
    const char* tile = (const char*)tileq;
    const int h0  = s*8 + p*2;
    const float2 bb1 = *(const float2*)(b1 + h0);
    const float2 bb3 = *(const float2*)(b3 + h0);
    const float2 bb5 = *(const float2*)(b5 + h0);
    // tap8 source stays in global (L2-hot): byte addr c*4608 + s*144+128+p*4
    const ushort* t8base = P5 + (size_t)s*72 + 64 + p*2;

    #pragma unroll
    for (int cc = 0; cc < 4; ++cc) {
        const int wl = cc*64 + wl0;
        const int n  = g*256 + wl;

        // this word's chars: 5 aligned int4 from global (L2-hot, 80 B)
        int cw[WW];
        {
            const int4* cp = (const int4*)(chars + n * WW);
            #pragma unroll
            for (int i = 0; i < 5; ++i) {
                int4 v = cp[i];
                cw[i*4+0] = v.x; cw[i*4+1] = v.y;
                cw[i*4+2] = v.z; cw[i*4+3] = v.w;
            }
        }

        float a3[2][3], a5[2][5], m1[2], m3[2], m5[2];
        #pragma unroll
        for (int i = 0; i < 2; ++i) {
            a3[i][0] = 0.f; a5[i][0] = 0.f; a5[i][1] = 0.f;
            m1[i] = -1e30f; m3[i] = -1e30f; m5[i] = -1e30f;
        }

        // t8 ring prefetch (distance 3, global/L2)
        unsigned t8r[4];
        t8r[0] = *(const unsigned*)(t8base + cw[0]*UNIT);
        t8r[1] = *(const unsigned*)(t8base + cw[1]*UNIT);
        t8r[2] = *(const unsigned*)(t8base + cw[2]*UNIT);

        uint4 qa[2], qb[2];
        {   // preload char 0 taps 0..7 from LDS
            int c0 = cw[0];
            qa[0] = *(const uint4*)(tile + c0*144 + p*32);
            qb[0] = *(const uint4*)(tile + c0*144 + p*32 + 16);
        }

        #pragma unroll
        for (int j = 0; j < WW; ++j) {
            const int cur = j & 1, nxt = cur ^ 1;
            if (j + 3 < WW)                 // refill t8 ring
                t8r[(j+3)&3] = *(const unsigned*)(t8base + cw[j+3]*UNIT);
            if (j + 1 < WW) {               // prefetch char j+1 from LDS
                int cn = cw[j+1];
                qa[nxt] = *(const uint4*)(tile + cn*144 + p*32);
                qb[nxt] = *(const uint4*)(tile + cn*144 + p*32 + 16);
            }
            float t8lo = blo(t8r[j&3]), t8hi = bhi(t8r[j&3]);
            STEP(j, qa[cur], t8lo, a3[0], a5[0], m1[0], m3[0], m5[0]);
            STEP(j, qb[cur], t8hi, a3[1], a5[1], m1[1], m3[1], m5[1]);
        }
        #pragma unroll
        for (int i = 0; i < 2; ++i) {
            m3[i] = fmaxf(m3[i], a3[i][(WW-1)%3]);     // pos 19
            m5[i] = fmaxf(m5[i], a5[i][(WW-2)%5]);     // pos 18
            m5[i] = fmaxf(m5[i], a5[i][(WW-1)%5]);     // pos 19
        }

        unsigned* op = (unsigned*)(outs + (size_t)n * K3 + h0);
        op[0*(HH/2)] = pack2(fmaxf(m1[0]+bb1.x, 0.f), fmaxf(m1[1]+bb1.y, 0.f));
        op[1*(HH/2)] = pack2(fmaxf(m3[0]+bb3.x, 0.f), fmaxf(m3[1]+bb3.y, 0.f));
        op[2*(HH/2)] = pack2(fmaxf(m5[0]+bb5.x, 0.f), fmaxf(m5[1]+bb5.y, 0.f));
    }
}

// ---------------------------------------------------------------------------
// K3: out = outs @ lw^T + lb via MFMA 16x16x32. 32m x 32n per wave,
// grid (256, 8) = 2048 single-wave blocks (2 waves/SIMD). 4-slot /
// distance-3 prefetch (R15: measured neutral vs distance-1 within +-2 us
// fill noise; kept). Fully unrolled K so slot indices fold (rule #20).
// A[m][k]: m=lane&15, k=quad*8+j. B[k][n]=lw[n][k]: n=lane&15, k=quad*8+j.
// C/D: col=lane&15, row=quad*4+reg.
// ---------------------------------------------------------------------------
__global__ __launch_bounds__(64) void gemm_out(
        const ushort* __restrict__ outs,   // [8192][768] bf16
        const ushort* __restrict__ lwb,    // [256][768] bf16
        const float* __restrict__ lb,
        float* __restrict__ out) {
    const int lane = threadIdx.x;
    const int m0 = blockIdx.x * 32;
    const int n0 = blockIdx.y * 32;
    const int mrow = lane & 15, quad = lane >> 4;

    f32x4 acc00 = (f32x4){0,0,0,0}, acc01 = (f32x4){0,0,0,0};
    f32x4 acc10 = (f32x4){0,0,0,0}, acc11 = (f32x4){0,0,0,0};
    const ushort* ap = outs + (size_t)(m0 + mrow) * K3 + quad * 8;
    const ushort* bp = lwb  + (size_t)(n0 + mrow) * K3 + quad * 8;

    bf16x8 A0[4], A1[4], B0[4], B1[4];
    #pragma unroll
    for (int pi = 0; pi < 3; ++pi) {
        A0[pi] = *(const bf16x8*)(ap + pi*32);
        A1[pi] = *(const bf16x8*)(ap + 16*K3 + pi*32);
        B0[pi] = *(const bf16x8*)(bp + pi*32);
        B1[pi] = *(const bf16x8*)(bp + 16*K3 + pi*32);
    }

    #pragma unroll
    for (int it = 0; it < K3/32; ++it) {
        const int sl = it & 3;
        const int nl = (it + 3) & 3;
        const int kn = (it + 3 < K3/32) ? (it + 3) * 32 : 0;   // wrap: harmless
        A0[nl] = *(const bf16x8*)(ap + kn);
        A1[nl] = *(const bf16x8*)(ap + 16*K3 + kn);
        B0[nl] = *(const bf16x8*)(bp + kn);
        B1[nl] = *(const bf16x8*)(bp + 16*K3 + kn);
        acc00 = __builtin_amdgcn_mfma_f32_16x16x32_bf16(A0[sl], B0[sl], acc00, 0, 0, 0);
        acc01 = __builtin_amdgcn_mfma_f32_16x16x32_bf16(A0[sl], B1[sl], acc01, 0, 0, 0);
        acc10 = __builtin_amdgcn_mfma_f32_16x16x32_bf16(A1[sl], B0[sl], acc10, 0, 0, 0);
        acc11 = __builtin_amdgcn_mfma_f32_16x16x32_bf16(A1[sl], B1[sl], acc11, 0, 0, 0);
    }

    #pragma unroll
    for (int i = 0; i < 2; ++i) {
        #pragma unroll
        for (int jn = 0; jn < 2; ++jn) {
            const f32x4 acc = (i==0) ? (jn==0 ? acc00 : acc01)
                                     : (jn==0 ? acc10 : acc11);
            int ncol = n0 + jn*16 + mrow;
            float lbv = lb[ncol];
            #pragma unroll
            for (int r = 0; r < 4; ++r)
                out[(size_t)(m0 + i*16 + quad*4 + r)*HH + ncol] = acc[r] + lbv;
        }
    }
}

// ---------------------------------------------------------------------------
extern "C" void kernel_launch(void* const* d_in, const int* in_sizes, int n_in,
                              void* d_out, int out_size, void* d_ws, size_t ws_size,
                              hipStream_t stream) {
    const int*   chars = (const int*)d_in[0];
    const float* emb   = (const float*)d_in[1];
    const float* w1    = (const float*)d_in[2];
    const float* b1    = (const float*)d_in[3];
    const float* w3    = (const float*)d_in[4];
    const float* b3    = (const float*)d_in[5];
    const float* w5    = (const float*)d_in[6];
    const float* b5    = (const float*)d_in[7];
    const float* lw    = (const float*)d_in[8];
    const float* lb    = (const float*)d_in[9];

    // ws: P5 [256][2304] bf16 (1.18MB) | wTp [64][2304] f32 (0.59MB)
    //   | outs [8192][768] bf16 (12.6MB) | lwb [256][768] bf16 (0.39MB)
    ushort* P5   = (ushort*)d_ws;
    float*  wTp  = (float*)(P5 + VOCAB * UNIT);
    ushort* outs = (ushort*)(wTp + EE * UNIT);
    ushort* lwb  = outs + (size_t)NW * K3;

    prep<<<768, 256, 0, stream>>>(w1, w3, w5, lw, wTp, lwb);
    build_tables<<<dim3(VOCAB/4, 9), 256, 0, stream>>>(emb, wTp, P5);
    conv_pool<<<dim3(NW/256, 32), 256, 0, stream>>>(chars, P5, b1, b3, b5, outs);
    gemm_out<<<dim3(NW/32, HH/32), 64, 0, stream>>>(outs, lwb, lb, (float*)d_out);
}

// Round 6
// 129.826 us; speedup vs baseline: 1.1517x; 1.1517x over previous
//
#include <hip/hip_runtime.h>
#include <hip/hip_bf16.h>

#define WW 20
#define NW 8192         // 64*128 words
#define VOCAB 256
#define EE 64
#define HH 256
#define K3 768          // 3*HH
#define UNIT 2304       // ushorts per vocab unit (P5) = 4608 B

typedef short bf16x8 __attribute__((ext_vector_type(8)));
typedef float f32x4  __attribute__((ext_vector_type(4)));

__device__ __forceinline__ ushort f2bs(float x) {
    __hip_bfloat16 h = __float2bfloat16(x);
    union { __hip_bfloat16 h; ushort u; } c; c.h = h; return c.u;
}
__device__ __forceinline__ float blo(unsigned u) {
    union { unsigned i; float f; } c; c.i = u << 16; return c.f;
}
__device__ __forceinline__ float bhi(unsigned u) {
    union { unsigned i; float f; } c; c.i = u & 0xffff0000u; return c.f;
}

// sliding-window update for one h given this char's 9 bf16 taps.
// j compile-time (fully unrolled caller) so %3/%5 indices and guards fold.
// R17 lesson: no f32x2 packing (VGPR 220 > 128 cliff, halved occupancy).
#define STEP(j, qq, t8v, a3, a5, mm1, mm3, mm5) {                        \
    float t0 = blo((qq).x), t1 = bhi((qq).x);                            \
    float t2 = blo((qq).y), t3 = bhi((qq).y);                            \
    float t4 = blo((qq).z), t5 = bhi((qq).z);                            \
    float t6 = blo((qq).w), t7 = bhi((qq).w);                            \
    mm1 = fmaxf(mm1, t0);                                                \
    if ((j) + 1 < WW) a3[((j)+1)%3] = t1;                                \
    a3[(j)%3] += t2;                                                     \
    if ((j) >= 1) { a3[((j)-1)%3] += t3;                                 \
                    mm3 = fmaxf(mm3, a3[((j)-1)%3]); }                   \
    if ((j) + 2 < WW) a5[((j)+2)%5] = t4;                                \
    if ((j) + 1 < WW) a5[((j)+1)%5] += t5;                               \
    a5[(j)%5] += t6;                                                     \
    if ((j) >= 1) a5[((j)-1)%5] += t7;                                   \
    if ((j) >= 2) { a5[((j)-2)%5] += (t8v);                              \
                    mm5 = fmaxf(mm5, a5[((j)-2)%5]); }                   \
}

// ---------------------------------------------------------------------------
// P5 layout (per vocab v, 2304 ushorts = 4608 B): 32 slices s of 144 B:
//   [hl 0..7][taps 0..7] (8 x 16 B rows), then [tap8 for hl 0..7] (16 B).
// bf16 kept deliberately (R12: f32 table doubled traffic + conflicts).
// R14 lesson: keep the wTp round-trip (fused divergent gather cost +6.6us).
// R18 lesson: tap8 must stay in LDS (global scatter = 335 MB L2 traffic).
// ---------------------------------------------------------------------------

// K0: prep. blocks 0..575: wTp[e][j] f32 (P5 column order);
//     blocks 576..767: lw f32 -> bf16;
//     blocks 768..1407: csb[i] = chars[i]*144 (pre-scaled byte offsets,
//     removes the *144 from conv's hot loop).
__global__ __launch_bounds__(256) void prep(
        const int* __restrict__ chars,
        const float* __restrict__ w1,
        const float* __restrict__ w3,
        const float* __restrict__ w5,
        const float* __restrict__ lw,
        float* __restrict__ wTp,
        ushort* __restrict__ lwb,
        int* __restrict__ csb) {
    const int bid = blockIdx.x;
    if (bid < 576) {
        int idx = bid * 256 + threadIdx.x;      // = e*2304 + j, 147456 total
        int e = idx / UNIT;
        int j = idx - e * UNIT;
        int s = j / 72, r = j - s * 72;
        int tap, h;
        if (r < 64) { tap = r & 7; h = s*8 + (r >> 3); }
        else        { tap = 8;     h = s*8 + (r - 64); }
        float v;
        if (tap == 0)      v = w1[h*EE + e];
        else if (tap <= 3) v = w3[(h*EE + e)*3 + (tap-1)];
        else               v = w5[(h*EE + e)*5 + (tap-4)];
        wTp[idx] = v;
    } else if (bid < 768) {
        int i = ((bid - 576) * 256 + threadIdx.x) * 4;
        float4 v = *(const float4*)(lw + i);
        ushort4 o4;
        o4.x = f2bs(v.x); o4.y = f2bs(v.y); o4.z = f2bs(v.z); o4.w = f2bs(v.w);
        *(ushort4*)(lwb + i) = o4;
    } else {
        int i = (bid - 768) * 256 + threadIdx.x;  // 640*256 = 163840 = NW*WW
        csb[i] = chars[i] * 144;
    }
}

// K1: P5[v][j] = sum_e emb[v][e] * wTp[e][j]. 4 vocab rows per block,
// grid (64, 9) x 256 thr. Coalesced streaming reads/writes.
__global__ __launch_bounds__(256) void build_tables(
        const float* __restrict__ emb,
        const float* __restrict__ wTp,
        ushort* __restrict__ P5) {
    __shared__ float emb_s[4][EE];
    const int v0 = blockIdx.x * 4;
    const int j  = blockIdx.y * 256 + threadIdx.x;
    const int t  = threadIdx.x;
    emb_s[t >> 6][t & 63] = emb[v0*EE + t];
    __syncthreads();

    float a0 = 0.f, a1 = 0.f, a2 = 0.f, a3 = 0.f;
    const float* wp = wTp + j;
    #pragma unroll 8
    for (int e = 0; e < EE; ++e) {
        float w = wp[e * UNIT];
        a0 += emb_s[0][e] * w; a1 += emb_s[1][e] * w;
        a2 += emb_s[2][e] * w; a3 += emb_s[3][e] * w;
    }
    P5[(size_t)(v0+0)*UNIT + j] = f2bs(a0);
    P5[(size_t)(v0+1)*UNIT + j] = f2bs(a1);
    P5[(size_t)(v0+2)*UNIT + j] = f2bs(a2);
    P5[(size_t)(v0+3)*UNIT + j] = f2bs(a3);
}

// ---------------------------------------------------------------------------
// K2: conv+relu+maxpool. R19 lane re-map: 8 lanes per word, ONE h each
// (lane = w*8 + r reads row c_w chunk r). Bank-quad index = (c_w + r) mod 8,
// so each word's 8 lanes cover all 8 quads exactly once -> every bank gets
// exactly 8 dwords per b128 wave-op, DETERMINISTICALLY conflict-free for
// any char distribution. (Old 4-lane/2-h map had quad = (c+2p) mod 8: only
// c mod 8 entropy over 16 random words -> measured 5.1M conflict cycles.)
// Same per-thread work (8 h-words), same LDS bytes, bit-identical math.
// tap8 = ds_read_u16 (128 B/wave). chars come pre-scaled (*144) from prep.
// LDS 36.9 KB -> 4 blocks/CU; VGPR well under 128 (11 accs vs 22).
// ---------------------------------------------------------------------------
__global__ __launch_bounds__(256, 4) void conv_pool(
        const int* __restrict__ csb,       // pre-scaled char byte offsets
        const ushort* __restrict__ P5,
        const float* __restrict__ b1,
        const float* __restrict__ b3,
        const float* __restrict__ b5,
        ushort* __restrict__ outs) {
    __shared__ uint4 tileq[2304];          // 36864 B table slice
    const int t = threadIdx.x;
    const int g = blockIdx.x;              // word group 0..31 (256 words)
    const int s = blockIdx.y;              // h slice   0..31

    {   // stage table slice: 2304 16-B chunks, 9 per thread (proven code)
        const char* src = (const char*)P5 + (size_t)s * 144;
        char* dst = (char*)tileq;
        #pragma unroll
        for (int i = 0; i < 9; ++i) {
            int c = i*256 + t;
            int v = c / 9, k = c - 9*v;
            *(uint4*)(dst + v*144 + k*16) =
                *(const uint4*)(src + (size_t)v*4608 + k*16);
        }
    }
    __syncthreads();

    const int r   = t & 7;                 // h lane 0..7 (chunk index)
    const int wl0 = t >> 3;                // word lane 0..31
    const char* tileQ = (const char*)tileq + r*16;        // taps 0..7 row
    const char* tileT = (const char*)tileq + 128 + r*2;   // tap8 ushort
    const int h = s*8 + r;
    const float bb1 = b1[h], bb3 = b3[h], bb5 = b5[h];

    #pragma unroll
    for (int cc = 0; cc < 8; ++cc) {
        const int wl = cc*32 + wl0;
        const int n  = g*256 + wl;

        // this word's pre-scaled char offsets: 5 aligned int4 (L2-hot, 80 B)
        int cw[WW];
        {
            const int4* cp = (const int4*)(csb + n * WW);
            #pragma unroll
            for (int i = 0; i < 5; ++i) {
                int4 v = cp[i];
                cw[i*4+0] = v.x; cw[i*4+1] = v.y;
                cw[i*4+2] = v.z; cw[i*4+3] = v.w;
            }
        }

        float a3[3], a5[5], m1, m3, m5;
        a3[0] = 0.f; a5[0] = 0.f; a5[1] = 0.f;
        m1 = -1e30f; m3 = -1e30f; m5 = -1e30f;

        uint4 q[2]; ushort t8[2];
        q[0]  = *(const uint4*)(tileQ + cw[0]);
        t8[0] = *(const ushort*)(tileT + cw[0]);

        #pragma unroll
        for (int j = 0; j < WW; ++j) {
            const int cur = j & 1, nxt = cur ^ 1;
            if (j + 1 < WW) {               // prefetch char j+1
                q[nxt]  = *(const uint4*)(tileQ + cw[j+1]);
                t8[nxt] = *(const ushort*)(tileT + cw[j+1]);
            }
            float t8v = blo(t8[cur]);
            STEP(j, q[cur], t8v, a3, a5, m1, m3, m5);
        }
        m3 = fmaxf(m3, a3[(WW-1)%3]);      // pos 19
        m5 = fmaxf(m5, a5[(WW-2)%5]);      // pos 18
        m5 = fmaxf(m5, a5[(WW-1)%5]);      // pos 19

        ushort* op = outs + (size_t)n * K3 + h;
        op[0*HH] = f2bs(fmaxf(m1 + bb1, 0.f));
        op[1*HH] = f2bs(fmaxf(m3 + bb3, 0.f));
        op[2*HH] = f2bs(fmaxf(m5 + bb5, 0.f));
    }
}

// ---------------------------------------------------------------------------
// K3: out = outs @ lw^T + lb via MFMA 16x16x32. 32m x 32n per wave,
// grid (256, 8) = 2048 single-wave blocks (2 waves/SIMD). 4-slot /
// distance-3 prefetch (R15: neutral vs distance-1 within noise; kept).
// A[m][k]: m=lane&15, k=quad*8+j. B[k][n]=lw[n][k]: n=lane&15, k=quad*8+j.
// C/D: col=lane&15, row=quad*4+reg.
// ---------------------------------------------------------------------------
__global__ __launch_bounds__(64) void gemm_out(
        const ushort* __restrict__ outs,   // [8192][768] bf16
        const ushort* __restrict__ lwb,    // [256][768] bf16
        const float* __restrict__ lb,
        float* __restrict__ out) {
    const int lane = threadIdx.x;
    const int m0 = blockIdx.x * 32;
    const int n0 = blockIdx.y * 32;
    const int mrow = lane & 15, quad = lane >> 4;

    f32x4 acc00 = (f32x4){0,0,0,0}, acc01 = (f32x4){0,0,0,0};
    f32x4 acc10 = (f32x4){0,0,0,0}, acc11 = (f32x4){0,0,0,0};
    const ushort* ap = outs + (size_t)(m0 + mrow) * K3 + quad * 8;
    const ushort* bp = lwb  + (size_t)(n0 + mrow) * K3 + quad * 8;

    bf16x8 A0[4], A1[4], B0[4], B1[4];
    #pragma unroll
    for (int pi = 0; pi < 3; ++pi) {
        A0[pi] = *(const bf16x8*)(ap + pi*32);
        A1[pi] = *(const bf16x8*)(ap + 16*K3 + pi*32);
        B0[pi] = *(const bf16x8*)(bp + pi*32);
        B1[pi] = *(const bf16x8*)(bp + 16*K3 + pi*32);
    }

    #pragma unroll
    for (int it = 0; it < K3/32; ++it) {
        const int sl = it & 3;
        const int nl = (it + 3) & 3;
        const int kn = (it + 3 < K3/32) ? (it + 3) * 32 : 0;   // wrap: harmless
        A0[nl] = *(const bf16x8*)(ap + kn);
        A1[nl] = *(const bf16x8*)(ap + 16*K3 + kn);
        B0[nl] = *(const bf16x8*)(bp + kn);
        B1[nl] = *(const bf16x8*)(bp + 16*K3 + kn);
        acc00 = __builtin_amdgcn_mfma_f32_16x16x32_bf16(A0[sl], B0[sl], acc00, 0, 0, 0);
        acc01 = __builtin_amdgcn_mfma_f32_16x16x32_bf16(A0[sl], B1[sl], acc01, 0, 0, 0);
        acc10 = __builtin_amdgcn_mfma_f32_16x16x32_bf16(A1[sl], B0[sl], acc10, 0, 0, 0);
        acc11 = __builtin_amdgcn_mfma_f32_16x16x32_bf16(A1[sl], B1[sl], acc11, 0, 0, 0);
    }

    #pragma unroll
    for (int i = 0; i < 2; ++i) {
        #pragma unroll
        for (int jn = 0; jn < 2; ++jn) {
            const f32x4 acc = (i==0) ? (jn==0 ? acc00 : acc01)
                                     : (jn==0 ? acc10 : acc11);
            int ncol = n0 + jn*16 + mrow;
            float lbv = lb[ncol];
            #pragma unroll
            for (int r = 0; r < 4; ++r)
                out[(size_t)(m0 + i*16 + quad*4 + r)*HH + ncol] = acc[r] + lbv;
        }
    }
}

// ---------------------------------------------------------------------------
extern "C" void kernel_launch(void* const* d_in, const int* in_sizes, int n_in,
                              void* d_out, int out_size, void* d_ws, size_t ws_size,
                              hipStream_t stream) {
    const int*   chars = (const int*)d_in[0];
    const float* emb   = (const float*)d_in[1];
    const float* w1    = (const float*)d_in[2];
    const float* b1    = (const float*)d_in[3];
    const float* w3    = (const float*)d_in[4];
    const float* b3    = (const float*)d_in[5];
    const float* w5    = (const float*)d_in[6];
    const float* b5    = (const float*)d_in[7];
    const float* lw    = (const float*)d_in[8];
    const float* lb    = (const float*)d_in[9];

    // ws: P5 [256][2304] bf16 (1.18MB) | wTp [64][2304] f32 (0.59MB)
    //   | outs [8192][768] bf16 (12.6MB) | lwb [256][768] bf16 (0.39MB)
    //   | csb [8192*20] int (0.66MB)
    ushort* P5   = (ushort*)d_ws;
    float*  wTp  = (float*)(P5 + VOCAB * UNIT);
    ushort* outs = (ushort*)(wTp + EE * UNIT);
    ushort* lwb  = outs + (size_t)NW * K3;
    int*    csb  = (int*)(lwb + (size_t)VOCAB * K3);

    prep<<<1408, 256, 0, stream>>>(chars, w1, w3, w5, lw, wTp, lwb, csb);
    build_tables<<<dim3(VOCAB/4, 9), 256, 0, stream>>>(emb, wTp, P5);
    conv_pool<<<dim3(NW/256, 32), 256, 0, stream>>>(csb, P5, b1, b3, b5, outs);
    gemm_out<<<dim3(NW/32, HH/32), 64, 0, stream>>>(outs, lwb, lb, (float*)d_out);
}